// Round 5
// baseline (6564.846 us; speedup 1.0000x reference)
//
#include <hip/hip_runtime.h>
#include <stdint.h>

// SkipGRU: T=384, B=48, C=H=256, L=2.
// R5: rec_layer = 4 WGs per batch element (grid 192, block 512 = 8 waves).
// R4 established: single-WG streaming is bound by per-CU L2 return BW
// (~52 B/cyc). R5 splits the 786 KB/step W stream over 4 CUs (196 KB each,
// R4's coalesced pattern) and pays a cheap handshake: R1's proven recipe
// (single-thread spin, s_sleep backoff) on one release-counter per batch.
// Skip steps: no W stream, no barriers, no exchange (bu=0 -> h unchanged).

#define T_STEPS 384

__device__ __forceinline__ float sigm_(float x) { return 1.f / (1.f + __expf(-x)); }
__device__ __forceinline__ float tanh_(float x) {
    float ax = fabsf(x);
    float e  = __expf(-2.f * ax);
    float r  = (1.f - e) / (1.f + e);
    return copysignf(r, x);
}

// ---------------------------------------------------------------------------
// GEMM: O[m][n] = sum_k X[m][k] * W[n][k] + B[n];  M=18432, N=768, K=256.
// (unchanged; both GEMMs together ~215 us, not the bottleneck)
// ---------------------------------------------------------------------------
__global__ __launch_bounds__(256, 2) void gemm_nt(const float* __restrict__ X,
                                                  const float* __restrict__ W,
                                                  const float* __restrict__ B,
                                                  float* __restrict__ O)
{
    __shared__ float As[32 * 140];
    __shared__ float Bs[32 * 68];

    const int tid = threadIdx.x;
    const int tx  = tid & 15;
    const int ty  = tid >> 4;
    const int n0  = blockIdx.x * 64;
    const int m0  = blockIdx.y * 128;

    float acc[8][4];
#pragma unroll
    for (int i = 0; i < 8; ++i)
#pragma unroll
        for (int j = 0; j < 4; ++j) acc[i][j] = 0.f;

    const float4 bias4 = *reinterpret_cast<const float4*>(B + n0 + tx * 4);

    for (int kc = 0; kc < 8; ++kc) {
        const int k0 = kc * 32;
        float4 a[4], bb[2];
#pragma unroll
        for (int j = 0; j < 4; ++j) {
            int f = tid + 256 * j, r = f >> 3, cq = f & 7;
            a[j] = *reinterpret_cast<const float4*>(X + (size_t)(m0 + r) * 256 + k0 + cq * 4);
        }
#pragma unroll
        for (int j = 0; j < 2; ++j) {
            int f = tid + 256 * j, r = f >> 3, cq = f & 7;
            bb[j] = *reinterpret_cast<const float4*>(W + (size_t)(n0 + r) * 256 + k0 + cq * 4);
        }
        __syncthreads();
#pragma unroll
        for (int j = 0; j < 4; ++j) {
            int f = tid + 256 * j, r = f >> 3, cq = f & 7;
            As[(cq * 4 + 0) * 140 + r] = a[j].x;
            As[(cq * 4 + 1) * 140 + r] = a[j].y;
            As[(cq * 4 + 2) * 140 + r] = a[j].z;
            As[(cq * 4 + 3) * 140 + r] = a[j].w;
        }
#pragma unroll
        for (int j = 0; j < 2; ++j) {
            int f = tid + 256 * j, r = f >> 3, cq = f & 7;
            Bs[(cq * 4 + 0) * 68 + r] = bb[j].x;
            Bs[(cq * 4 + 1) * 68 + r] = bb[j].y;
            Bs[(cq * 4 + 2) * 68 + r] = bb[j].z;
            Bs[(cq * 4 + 3) * 68 + r] = bb[j].w;
        }
        __syncthreads();
#pragma unroll 8
        for (int kk = 0; kk < 32; ++kk) {
            float4 av0 = *reinterpret_cast<const float4*>(As + kk * 140 + ty * 8);
            float4 av1 = *reinterpret_cast<const float4*>(As + kk * 140 + ty * 8 + 4);
            float4 bv  = *reinterpret_cast<const float4*>(Bs + kk * 68 + tx * 4);
            float am[8] = {av0.x, av0.y, av0.z, av0.w, av1.x, av1.y, av1.z, av1.w};
            float bn[4] = {bv.x, bv.y, bv.z, bv.w};
#pragma unroll
            for (int i = 0; i < 8; ++i)
#pragma unroll
                for (int j = 0; j < 4; ++j) acc[i][j] = fmaf(am[i], bn[j], acc[i][j]);
        }
    }
#pragma unroll
    for (int i = 0; i < 8; ++i) {
        int row = m0 + ty * 8 + i;
        float4 o;
        o.x = acc[i][0] + bias4.x;
        o.y = acc[i][1] + bias4.y;
        o.z = acc[i][2] + bias4.z;
        o.w = acc[i][3] + bias4.w;
        *reinterpret_cast<float4*>(O + (size_t)row * 768 + n0 + tx * 4) = o;
    }
}

// ---------------------------------------------------------------------------
// Recurrence: grid 192 (p = blk/48 in 0..3, b = blk%48), block 512 (8 waves).
// WG p owns h-columns [p*64, p*64+64) and streams the 192 W_hh rows
// {gate*256 + p*64 + j} each step, R4-style: wave w handles flat row idx
// [w*24, w*24+24), 4 rows/iter (q = lane>>4 picks row, s = lane&15 picks
// k-16th; per load instr 16 lanes cover 256 contiguous bytes of one row).
// Wave 0 does the per-column gate math; partner halves of h arrive via
// agent-scope XH slots + one release-counter per batch (single-thread spin).
// ---------------------------------------------------------------------------
__global__ __launch_bounds__(512) void rec_layer(
    const float* __restrict__ GI, float* __restrict__ Yout,
    const float* __restrict__ whh, const float* __restrict__ bhh,
    const float* __restrict__ lwl, const float* __restrict__ lbl,
    const float* __restrict__ hid,
    float* XH, float* PD, int* FLG,
    float* __restrict__ hsout, float* __restrict__ tuout)
{
    __shared__ float hcur[256];
    __shared__ float gates[192];
    __shared__ float pdsum_s;

    const int tid  = threadIdx.x;
    const int lane = tid & 63;
    const int w    = tid >> 6;    // wave 0..7
    const int q    = lane >> 4;   // row-in-quad 0..3
    const int s    = lane & 15;   // k-sixteenth 0..15
    const int b    = blockIdx.x % 48;
    const int p    = blockIdx.x / 48;   // quarter 0..3; partners {b,b+48,b+96,b+144}

    // wave-0 per-column state (column c = p*64 + lane)
    float hreg = 0.f, lwc = 0.f, bhr = 0.f, bhz = 0.f, bhn = 0.f;
    if (w == 0) {
        const int c = p * 64 + lane;
        hreg = hid[c];
        lwc  = lwl[c];
        bhr  = bhh[c]; bhz = bhh[256 + c]; bhn = bhh[512 + c];
    }
    if (tid < 256) hcur[tid] = hid[tid];
    const float lbv = lbl[0];
    __syncthreads();

    float u = 1.f, d = 0.f;
    bool  skip = false;
    int   ns = 0;  // non-skip step counter; XH/PD slot parity = ns&1

    float* XHb = XH + b * 512;    // [parity][256]
    float* PDb = PD + b * 8;      // [parity][4]
    int*   cnt = FLG + b;         // release-counter; target 4*(ns+1)

    for (int t = 0; t < T_STEPS; ++t) {
        const size_t yrow = ((size_t)t * 48 + b) * 256;

        if (skip) {
            // u<0.5 -> bu=0 -> h, d unchanged; u = clip(u+d,0,1). No sync.
            if (w == 0) {
                Yout[yrow + p * 64 + lane] = hreg;
                if (t == T_STEPS - 1) hsout[b * 256 + p * 64 + lane] = hreg;
            }
            if (p == 0 && tid == 0) tuout[b * 768 + t] = 0.f;
            u = fminf(fmaxf(u + d, 0.f), 1.f);
            skip = (u < 0.5f);
            continue;
        }

        const float bu = rintf(u);  // RNE == jnp.round

        // gi prefetch for our 64 columns (wave 0), consumed after B1
        float gir = 0.f, giz = 0.f, gin = 0.f;
        if (w == 0) {
            const size_t gb = ((size_t)t * 48 + b) * 768 + p * 64 + lane;
            gir = GI[gb]; giz = GI[gb + 256]; gin = GI[gb + 512];
        }

        // h fragment for k-slice s
        const float4 h0 = *reinterpret_cast<const float4*>(hcur + 4 * s);
        const float4 h1 = *reinterpret_cast<const float4*>(hcur + 4 * s + 64);
        const float4 h2 = *reinterpret_cast<const float4*>(hcur + 4 * s + 128);
        const float4 h3 = *reinterpret_cast<const float4*>(hcur + 4 * s + 192);

        // stream this WG's 192 rows: wave w -> flat idx [w*24, w*24+24)
#pragma unroll
        for (int it = 0; it < 6; ++it) {
            const int idx = w * 24 + it * 4 + q;                 // 0..191
            const int row = (idx >> 6) * 256 + p * 64 + (idx & 63);
            const float4* Wp = reinterpret_cast<const float4*>(whh + (size_t)row * 256 + s * 4);
            const float4 w0 = Wp[0];
            const float4 w1 = Wp[16];
            const float4 w2 = Wp[32];
            const float4 w3 = Wp[48];
            float a;
            a = w0.x * h0.x;          a = fmaf(w0.y, h0.y, a);
            a = fmaf(w0.z, h0.z, a);  a = fmaf(w0.w, h0.w, a);
            a = fmaf(w1.x, h1.x, a);  a = fmaf(w1.y, h1.y, a);
            a = fmaf(w1.z, h1.z, a);  a = fmaf(w1.w, h1.w, a);
            a = fmaf(w2.x, h2.x, a);  a = fmaf(w2.y, h2.y, a);
            a = fmaf(w2.z, h2.z, a);  a = fmaf(w2.w, h2.w, a);
            a = fmaf(w3.x, h3.x, a);  a = fmaf(w3.y, h3.y, a);
            a = fmaf(w3.z, h3.z, a);  a = fmaf(w3.w, h3.w, a);
            // reduce over the 16 k-subs (offsets stay inside the 16-lane group)
            a += __shfl_xor(a, 1); a += __shfl_xor(a, 2);
            a += __shfl_xor(a, 4); a += __shfl_xor(a, 8);
            if (s == 0) gates[idx] = a;
        }

        __syncthreads();  // B1: gates complete, hcur reads of this step done

        if (w == 0) {
            const float ar = gates[lane];
            const float az = gates[64 + lane];
            const float an = gates[128 + lane];
            const float rr = sigm_(gir + ar + bhr);
            const float zz = sigm_(giz + az + bhz);
            const float nn = tanh_(gin + rr * (an + bhn));
            const float nh = ((1.f - zz) * nn + zz * hreg) * bu;
            hreg = nh;
            hcur[p * 64 + lane] = nh;
            Yout[yrow + p * 64 + lane] = nh;
            if (t == T_STEPS - 1) hsout[b * 256 + p * 64 + lane] = nh;
            __hip_atomic_store(XHb + (ns & 1) * 256 + p * 64 + lane, nh,
                               __ATOMIC_RELAXED, __HIP_MEMORY_SCOPE_AGENT);
            float pdv = nh * lwc;
            pdv += __shfl_xor(pdv, 1);  pdv += __shfl_xor(pdv, 2);
            pdv += __shfl_xor(pdv, 4);  pdv += __shfl_xor(pdv, 8);
            pdv += __shfl_xor(pdv, 16); pdv += __shfl_xor(pdv, 32);
            if (lane == 0)
                __hip_atomic_store(PDb + (ns & 1) * 4 + p, pdv,
                                   __ATOMIC_RELAXED, __HIP_MEMORY_SCOPE_AGENT);
        }
        if (p == 0 && tid == 0) tuout[b * 768 + t] = bu;

        __syncthreads();  // B2: vmcnt drained -> wave0's XH/PD stores complete

        if (tid == 0) {
            __hip_atomic_fetch_add(cnt, 1, __ATOMIC_RELEASE, __HIP_MEMORY_SCOPE_AGENT);
            const int tgt = 4 * (ns + 1);
            while (__hip_atomic_load(cnt, __ATOMIC_ACQUIRE, __HIP_MEMORY_SCOPE_AGENT) < tgt) {
                __builtin_amdgcn_s_sleep(1);   // single-thread spin: R1-proven stable
            }
        }
        __syncthreads();  // B3: all partners' step ns published

        if (w >= 1 && w <= 3) {
            const int qp = (p + w) & 3;
            float v = __hip_atomic_load(XHb + (ns & 1) * 256 + qp * 64 + lane,
                                        __ATOMIC_RELAXED, __HIP_MEMORY_SCOPE_AGENT);
            hcur[qp * 64 + lane] = v;
        }
        if (tid == 0) {
            float p0 = __hip_atomic_load(PDb + (ns & 1) * 4 + 0, __ATOMIC_RELAXED, __HIP_MEMORY_SCOPE_AGENT);
            float p1 = __hip_atomic_load(PDb + (ns & 1) * 4 + 1, __ATOMIC_RELAXED, __HIP_MEMORY_SCOPE_AGENT);
            float p2 = __hip_atomic_load(PDb + (ns & 1) * 4 + 2, __ATOMIC_RELAXED, __HIP_MEMORY_SCOPE_AGENT);
            float p3 = __hip_atomic_load(PDb + (ns & 1) * 4 + 3, __ATOMIC_RELAXED, __HIP_MEMORY_SCOPE_AGENT);
            pdsum_s = ((p0 + p1) + (p2 + p3));  // fixed order -> identical in all 4 WGs
        }

        __syncthreads();  // B4: hcur complete, pdsum ready

        const float dns = sigm_(pdsum_s + lbv);
        u = dns * bu;
        d = dns;
        skip = (u < 0.5f);
        ns++;
    }
}

// ---------------------------------------------------------------------------
extern "C" void kernel_launch(void* const* d_in, const int* in_sizes, int n_in,
                              void* d_out, int out_size, void* d_ws, size_t ws_size,
                              hipStream_t stream)
{
    const float* x   = (const float*)d_in[0];  // (384,48,256)
    const float* hid = (const float*)d_in[1];  // (2,1,256)
    const float* wih = (const float*)d_in[2];  // (2,768,256)
    const float* whh = (const float*)d_in[3];  // (2,768,256)
    const float* bih = (const float*)d_in[4];  // (2,768)
    const float* bhh = (const float*)d_in[5];  // (2,768)
    const float* lw  = (const float*)d_in[6];  // (2,1,256)
    const float* lb  = (const float*)d_in[7];  // (2,1)
    float* out = (float*)d_out;

    float* ws   = (float*)d_ws;
    float* GI   = ws;                               // 18432*768
    float* Y0   = GI + (size_t)18432 * 768;         // 18432*256
    float* XH0  = Y0 + (size_t)18432 * 256;         // 48*2*256
    float* XH1  = XH0 + 48 * 512;
    float* PD0  = XH1 + 48 * 512;                   // 48*2*4
    float* PD1  = PD0 + 48 * 8;
    int*   FLG0 = (int*)(PD1 + 48 * 8);             // 48 counters per layer
    int*   FLG1 = FLG0 + 48;

    float* OUTy = out;                              // (384,48,256)
    float* HS   = out + (size_t)18432 * 256;        // (2,48,256)
    float* TU   = HS + 2 * 48 * 256;                // (48,768): layer0 cols 0..383

    // counters must start at 0 regardless of workspace poison
    hipMemsetAsync(FLG0, 0, 2 * 48 * sizeof(int), stream);

    dim3 ggrid(12, 144), gblk(256);
    gemm_nt<<<ggrid, gblk, 0, stream>>>(x, wih, bih, GI);
    rec_layer<<<192, 512, 0, stream>>>(GI, Y0, whh, bhh, lw, lb, hid,
                                       XH0, PD0, FLG0, HS, TU);
    gemm_nt<<<ggrid, gblk, 0, stream>>>(Y0, wih + 196608, bih + 768, GI);
    rec_layer<<<192, 512, 0, stream>>>(GI, OUTy, whh + 196608, bhh + 768,
                                       lw + 256, lb + 1, hid + 256,
                                       XH1, PD1, FLG1, HS + 12288, TU + 384);
}

// Round 6
// 3509.016 us; speedup vs baseline: 1.8709x; 1.8709x over previous
//
#include <hip/hip_runtime.h>
#include <stdint.h>

// SkipGRU: T=384, B=48, C=H=256, L=2.
// R6: rec_layer = 2 WGs per batch (grid 96, block 256, 1 wave/SIMD -> 512-VGPR cap).
// Each lane holds 384 W_hh floats (3 gates x its 128-k half of one column) in
// VGPRs, FORCED resident via empty-asm "+v" pins (R1/R2/R3: the allocator sinks
// plain loads; pinned values are opaque and must stay live). Zero W memory
// traffic per step (R4 proved the stream is per-CU-L2-BW bound at 6.3 us/step).
// Handshake: R1's stable single-thread release/acquire spin, hardened with
// per-WG flag words in private 256-B lines (R5's shared-line counters caused
// cross-XCD false sharing -> 33 ms outliers). Skip steps: no barriers at all.

#define T_STEPS 384

__device__ __forceinline__ float sigm_(float x) { return 1.f / (1.f + __expf(-x)); }
__device__ __forceinline__ float tanh_(float x) {
    float ax = fabsf(x);
    float e  = __expf(-2.f * ax);
    float r  = (1.f - e) / (1.f + e);
    return copysignf(r, x);
}

// ---------------------------------------------------------------------------
// GEMM: O[m][n] = sum_k X[m][k] * W[n][k] + B[n];  M=18432, N=768, K=256.
// (unchanged; both GEMMs together ~215 us)
// ---------------------------------------------------------------------------
__global__ __launch_bounds__(256, 2) void gemm_nt(const float* __restrict__ X,
                                                  const float* __restrict__ W,
                                                  const float* __restrict__ B,
                                                  float* __restrict__ O)
{
    __shared__ float As[32 * 140];
    __shared__ float Bs[32 * 68];

    const int tid = threadIdx.x;
    const int tx  = tid & 15;
    const int ty  = tid >> 4;
    const int n0  = blockIdx.x * 64;
    const int m0  = blockIdx.y * 128;

    float acc[8][4];
#pragma unroll
    for (int i = 0; i < 8; ++i)
#pragma unroll
        for (int j = 0; j < 4; ++j) acc[i][j] = 0.f;

    const float4 bias4 = *reinterpret_cast<const float4*>(B + n0 + tx * 4);

    for (int kc = 0; kc < 8; ++kc) {
        const int k0 = kc * 32;
        float4 a[4], bb[2];
#pragma unroll
        for (int j = 0; j < 4; ++j) {
            int f = tid + 256 * j, r = f >> 3, cq = f & 7;
            a[j] = *reinterpret_cast<const float4*>(X + (size_t)(m0 + r) * 256 + k0 + cq * 4);
        }
#pragma unroll
        for (int j = 0; j < 2; ++j) {
            int f = tid + 256 * j, r = f >> 3, cq = f & 7;
            bb[j] = *reinterpret_cast<const float4*>(W + (size_t)(n0 + r) * 256 + k0 + cq * 4);
        }
        __syncthreads();
#pragma unroll
        for (int j = 0; j < 4; ++j) {
            int f = tid + 256 * j, r = f >> 3, cq = f & 7;
            As[(cq * 4 + 0) * 140 + r] = a[j].x;
            As[(cq * 4 + 1) * 140 + r] = a[j].y;
            As[(cq * 4 + 2) * 140 + r] = a[j].z;
            As[(cq * 4 + 3) * 140 + r] = a[j].w;
        }
#pragma unroll
        for (int j = 0; j < 2; ++j) {
            int f = tid + 256 * j, r = f >> 3, cq = f & 7;
            Bs[(cq * 4 + 0) * 68 + r] = bb[j].x;
            Bs[(cq * 4 + 1) * 68 + r] = bb[j].y;
            Bs[(cq * 4 + 2) * 68 + r] = bb[j].z;
            Bs[(cq * 4 + 3) * 68 + r] = bb[j].w;
        }
        __syncthreads();
#pragma unroll 8
        for (int kk = 0; kk < 32; ++kk) {
            float4 av0 = *reinterpret_cast<const float4*>(As + kk * 140 + ty * 8);
            float4 av1 = *reinterpret_cast<const float4*>(As + kk * 140 + ty * 8 + 4);
            float4 bv  = *reinterpret_cast<const float4*>(Bs + kk * 68 + tx * 4);
            float am[8] = {av0.x, av0.y, av0.z, av0.w, av1.x, av1.y, av1.z, av1.w};
            float bn[4] = {bv.x, bv.y, bv.z, bv.w};
#pragma unroll
            for (int i = 0; i < 8; ++i)
#pragma unroll
                for (int j = 0; j < 4; ++j) acc[i][j] = fmaf(am[i], bn[j], acc[i][j]);
        }
    }
#pragma unroll
    for (int i = 0; i < 8; ++i) {
        int row = m0 + ty * 8 + i;
        float4 o;
        o.x = acc[i][0] + bias4.x;
        o.y = acc[i][1] + bias4.y;
        o.z = acc[i][2] + bias4.z;
        o.w = acc[i][3] + bias4.w;
        *reinterpret_cast<float4*>(O + (size_t)row * 768 + n0 + tx * 4) = o;
    }
}

// ---------------------------------------------------------------------------
// Recurrence: grid 96 (p = blk/48 in {0,1}, b = blk%48 -> partners same XCD),
// block 256 = 4 waves, 1 wave/SIMD. Wave w, col-group g = lane&31 ->
// column c = p*128 + w*32 + g; k-half s = lane>>5 -> k in [s*128, s*128+128).
// Per lane: Wreg[384] = rows {c, 256+c, 512+c} over its k-half, asm-pinned.
// Both 32-lane halves compute identical nh (shfl_xor(32) merges k-halves).
// XH slot per batch: 1024-float aligned region, [parity*512 + 0..256) = h,
// [parity*512 + 256+p] = pd. Flags: FLG[b*64 + p*32], private 256-B lines.
// ---------------------------------------------------------------------------
__global__ __launch_bounds__(256, 1) void rec_layer(
    const float* __restrict__ GI, float* __restrict__ Yout,
    const float* __restrict__ whh, const float* __restrict__ bhh,
    const float* __restrict__ lwl, const float* __restrict__ lbl,
    const float* __restrict__ hid,
    float* XH, int* FLG,
    float* __restrict__ hsout, float* __restrict__ tuout)
{
    __shared__ float hcur[256];
    __shared__ float pdw[4];

    const int tid  = threadIdx.x;
    const int lane = tid & 63;
    const int w    = tid >> 6;        // wave 0..3
    const int g    = lane & 31;       // column within wave's group
    const int s    = lane >> 5;       // k-half 0..1
    const int b    = blockIdx.x % 48;
    const int p    = blockIdx.x / 48; // half 0..1; partner block = b + 48*(1-p)
    const int c    = p * 128 + w * 32 + g;

    // ---- W_hh fragment -> 384 pinned VGPRs ----
    float Wreg[384];
    {
        const float4* wr = reinterpret_cast<const float4*>(whh + (size_t)c * 256 + s * 128);
        const float4* wz = reinterpret_cast<const float4*>(whh + (size_t)(256 + c) * 256 + s * 128);
        const float4* wn = reinterpret_cast<const float4*>(whh + (size_t)(512 + c) * 256 + s * 128);
#pragma unroll
        for (int i = 0; i < 32; ++i) {
            float4 v = wr[i];
            Wreg[4 * i + 0] = v.x; Wreg[4 * i + 1] = v.y;
            Wreg[4 * i + 2] = v.z; Wreg[4 * i + 3] = v.w;
        }
#pragma unroll
        for (int i = 0; i < 32; ++i) {
            float4 v = wz[i];
            Wreg[128 + 4 * i + 0] = v.x; Wreg[128 + 4 * i + 1] = v.y;
            Wreg[128 + 4 * i + 2] = v.z; Wreg[128 + 4 * i + 3] = v.w;
        }
#pragma unroll
        for (int i = 0; i < 32; ++i) {
            float4 v = wn[i];
            Wreg[256 + 4 * i + 0] = v.x; Wreg[256 + 4 * i + 1] = v.y;
            Wreg[256 + 4 * i + 2] = v.z; Wreg[256 + 4 * i + 3] = v.w;
        }
    }
    // pin: make each value opaque so the allocator cannot sink/remat the loads
#pragma unroll
    for (int i = 0; i < 384; ++i) asm volatile("" : "+v"(Wreg[i]));

    const float bhr = bhh[c], bhz = bhh[256 + c], bhn = bhh[512 + c];
    const float lwc = lwl[c];
    const float lbv = lbl[0];

    if (tid < 256) hcur[tid] = hid[tid];
    float hreg = hid[c];
    __syncthreads();

    float u = 1.f, d = 0.f;
    bool  skip = false;
    int   ns = 0;   // non-skip step counter; slot parity = ns&1

    float* XHb   = XH + (size_t)b * 1024;
    int*   myfl  = FLG + b * 64 + p * 32;
    int*   ptfl  = FLG + b * 64 + (1 - p) * 32;

    for (int t = 0; t < T_STEPS; ++t) {
        const size_t yrow = ((size_t)t * 48 + b) * 256;

        if (skip) {
            // u<0.5 -> bu=0 -> h, d unchanged; u=clip(u+d,0,1). No sync.
            if (s == 0) {
                Yout[yrow + c] = hreg;
                if (t == T_STEPS - 1) hsout[b * 256 + c] = hreg;
            }
            if (p == 0 && tid == 0) tuout[b * 768 + t] = 0.f;
            u = fminf(fmaxf(u + d, 0.f), 1.f);
            skip = (u < 0.5f);
            continue;
        }

        const float bu = rintf(u);  // RNE == jnp.round

        // gi prefetch (both k-halves load identically -- broadcast dup)
        const size_t gb = ((size_t)t * 48 + b) * 768 + c;
        const float gir = GI[gb], giz = GI[gb + 256], gin = GI[gb + 512];

        // matvec over this lane's k-half: 384 FMAs on pinned VGPRs
        float ar = 0.f, az = 0.f, an = 0.f;
        const float4* h4 = reinterpret_cast<const float4*>(hcur + s * 128);
#pragma unroll
        for (int i = 0; i < 32; ++i) {
            const float4 hv = h4[i];
            ar = fmaf(Wreg[4 * i + 0], hv.x, ar);
            ar = fmaf(Wreg[4 * i + 1], hv.y, ar);
            ar = fmaf(Wreg[4 * i + 2], hv.z, ar);
            ar = fmaf(Wreg[4 * i + 3], hv.w, ar);
            az = fmaf(Wreg[128 + 4 * i + 0], hv.x, az);
            az = fmaf(Wreg[128 + 4 * i + 1], hv.y, az);
            az = fmaf(Wreg[128 + 4 * i + 2], hv.z, az);
            az = fmaf(Wreg[128 + 4 * i + 3], hv.w, az);
            an = fmaf(Wreg[256 + 4 * i + 0], hv.x, an);
            an = fmaf(Wreg[256 + 4 * i + 1], hv.y, an);
            an = fmaf(Wreg[256 + 4 * i + 2], hv.z, an);
            an = fmaf(Wreg[256 + 4 * i + 3], hv.w, an);
        }
        // merge the two k-halves (a+b vs b+a: bitwise-identical across halves)
        ar += __shfl_xor(ar, 32);
        az += __shfl_xor(az, 32);
        an += __shfl_xor(an, 32);

        // gate math on all lanes (halves identical)
        const float rr = sigm_(gir + ar + bhr);
        const float zz = sigm_(giz + az + bhz);
        const float nn = tanh_(gin + rr * (an + bhn));
        const float nh = ((1.f - zz) * nn + zz * hreg) * bu;
        hreg = nh;

        // pd partial: butterfly over 64 lanes = 2x(sum over 32 cols); *0.5 exact
        float pdv = nh * lwc;
        pdv += __shfl_xor(pdv, 1);  pdv += __shfl_xor(pdv, 2);
        pdv += __shfl_xor(pdv, 4);  pdv += __shfl_xor(pdv, 8);
        pdv += __shfl_xor(pdv, 16); pdv += __shfl_xor(pdv, 32);
        pdv *= 0.5f;
        if (lane == 0) pdw[w] = pdv;

        __syncthreads();  // B1: all matvec hcur reads + pdw writes done

        float* slot = XHb + (ns & 1) * 512;
        if (s == 0) {
            hcur[c] = nh;
            Yout[yrow + c] = nh;
            if (t == T_STEPS - 1) hsout[b * 256 + c] = nh;
            __hip_atomic_store(slot + c, nh, __ATOMIC_RELAXED, __HIP_MEMORY_SCOPE_AGENT);
        }
        const float ownpd = (pdw[0] + pdw[1]) + (pdw[2] + pdw[3]);
        if (tid == 0)
            __hip_atomic_store(slot + 256 + p, ownpd, __ATOMIC_RELAXED, __HIP_MEMORY_SCOPE_AGENT);
        if (p == 0 && tid == 0) tuout[b * 768 + t] = bu;

        __syncthreads();  // B2: every wave drains vmcnt -> all XH stores visible

        if (tid == 0) {
            __hip_atomic_store(myfl, ns + 1, __ATOMIC_RELEASE, __HIP_MEMORY_SCOPE_AGENT);
            while (__hip_atomic_load(ptfl, __ATOMIC_ACQUIRE, __HIP_MEMORY_SCOPE_AGENT) < ns + 1) {
                __builtin_amdgcn_s_sleep(1);
            }
        }
        __syncthreads();  // B3: partner's step published

        if (tid < 128) {
            const int qc = (1 - p) * 128 + tid;
            float v = __hip_atomic_load(slot + qc, __ATOMIC_RELAXED, __HIP_MEMORY_SCOPE_AGENT);
            hcur[qc] = v;
        }
        const float pb = __hip_atomic_load(slot + 256 + (1 - p),
                                           __ATOMIC_RELAXED, __HIP_MEMORY_SCOPE_AGENT);
        const float dns = sigm_((ownpd + pb) + lbv);  // commutative -> same in both WGs
        u = dns * bu;
        d = dns;
        skip = (u < 0.5f);
        ns++;

        __syncthreads();  // B4: partner half of hcur in place for next matvec
    }
}

// ---------------------------------------------------------------------------
extern "C" void kernel_launch(void* const* d_in, const int* in_sizes, int n_in,
                              void* d_out, int out_size, void* d_ws, size_t ws_size,
                              hipStream_t stream)
{
    const float* x   = (const float*)d_in[0];  // (384,48,256)
    const float* hid = (const float*)d_in[1];  // (2,1,256)
    const float* wih = (const float*)d_in[2];  // (2,768,256)
    const float* whh = (const float*)d_in[3];  // (2,768,256)
    const float* bih = (const float*)d_in[4];  // (2,768)
    const float* bhh = (const float*)d_in[5];  // (2,768)
    const float* lw  = (const float*)d_in[6];  // (2,1,256)
    const float* lb  = (const float*)d_in[7];  // (2,1)
    float* out = (float*)d_out;

    float* ws   = (float*)d_ws;
    float* GI   = ws;                               // 18432*768
    float* Y0   = GI + (size_t)18432 * 768;         // 18432*256
    float* XH0  = Y0 + (size_t)18432 * 256;         // 48*1024 per layer
    float* XH1  = XH0 + 48 * 1024;
    int*   FLG0 = (int*)(XH1 + 48 * 1024);          // 48*64 ints per layer
    int*   FLG1 = FLG0 + 48 * 64;

    float* OUTy = out;                              // (384,48,256)
    float* HS   = out + (size_t)18432 * 256;        // (2,48,256)
    float* TU   = HS + 2 * 48 * 256;                // (48,768)

    // flags must start at 0 regardless of workspace poison
    hipMemsetAsync(FLG0, 0, 2 * 48 * 64 * sizeof(int), stream);

    dim3 ggrid(12, 144), gblk(256);
    gemm_nt<<<ggrid, gblk, 0, stream>>>(x, wih, bih, GI);
    rec_layer<<<96, 256, 0, stream>>>(GI, Y0, whh, bhh, lw, lb, hid,
                                      XH0, FLG0, HS, TU);
    gemm_nt<<<ggrid, gblk, 0, stream>>>(Y0, wih + 196608, bih + 768, GI);
    rec_layer<<<96, 256, 0, stream>>>(GI, OUTy, whh + 196608, bhh + 768,
                                      lw + 256, lb + 1, hid + 256,
                                      XH1, FLG1, HS + 12288, TU + 384);
}